// Round 6
// baseline (81.323 us; speedup 1.0000x reference)
//
#include <hip/hip_runtime.h>

#define NB 2
#define NP 1024
#define NC 128
#define NG 7
#define NSM 48
#define BN (NB*NP)

#define OFF_ORIS 0
#define OFF_NORS (BN*3)
#define OFF_PUPS (2*BN*3)
#define OFF_POFF (OFF_PUPS + BN*16*3)
#define OFF_PU   (OFF_POFF + BN*3)

#define BN3(x,y,z) do { \
    float ss = __fadd_rn(__fadd_rn(__fmul_rn(x,x), __fmul_rn(y,y)), __fmul_rn(z,z)); \
    float nr = sqrtf(__fadd_rn(ss, 1e-8f)); \
    float dn = __fadd_rn(nr, 1e-10f); \
    x = __fdiv_rn(x, dn); y = __fdiv_rn(y, dn); z = __fdiv_rn(z, dn); \
} while (0)

// One WAVE per point (64-thread blocks). No inter-wave sync: rot frame held
// redundantly in every lane (butterfly reduce), first-48 extraction folded into
// the ballot loop, per-wave LDS atomicMax dedup, full-wave feat_off dots over
// the (typically ~7) winning cells. Barriers are single-wave (near-free).
__global__ __launch_bounds__(64) void kfused(const float* __restrict__ xyz,
                                             const float* __restrict__ feat,
                                             const float* __restrict__ W0, const float* __restrict__ b0,
                                             const float* __restrict__ W1, const float* __restrict__ b1,
                                             const float* __restrict__ W_unet,
                                             const int* __restrict__ index,
                                             float* __restrict__ out) {
    __shared__ int   sgidx[NSM];
    __shared__ int   scell[91];       // cell = (c0+c1)*7 + c2 <= 90
    __shared__ float sfo[NG*NG*3];
    __shared__ float spu[NG*NG*3];

    int p = blockIdx.x;
    int b = p >> 10, n = p & (NP - 1);
    int l = threadIdx.x;
    const float* xb = xyz + (size_t)b*3*NP;

    scell[l] = -1;
    if (l + 64 < 91) scell[l + 64] = -1;
    sfo[l] = 0.0f; sfo[l + 64] = 0.0f;
    if (l + 128 < NG*NG*3) sfo[l + 128] = 0.0f;

    // ---- center point (wave-uniform) ----
    float cx = xb[n], cy = xb[NP + n], cz = xb[2*NP + n];
    float cn = __fadd_rn(__fadd_rn(__fmul_rn(cx,cx), __fmul_rn(cy,cy)), __fmul_rn(cz,cz));

    // ---- matvec: butterfly reduce leaves full sums in ALL lanes ----
    float f0 = feat[p*NC + l];
    float f1 = feat[p*NC + 64 + l];
    float s0 = f0*W0[l]     + f1*W0[64+l];
    float s1 = f0*W0[128+l] + f1*W0[192+l];
    float s2 = f0*W0[256+l] + f1*W0[320+l];
    float s3 = f0*W1[l]     + f1*W1[64+l];
    float s4 = f0*W1[128+l] + f1*W1[192+l];
    float s5 = f0*W1[256+l] + f1*W1[320+l];
    for (int off = 32; off; off >>= 1) {
        s0 += __shfl_xor(s0, off);
        s1 += __shfl_xor(s1, off);
        s2 += __shfl_xor(s2, off);
        s3 += __shfl_xor(s3, off);
        s4 += __shfl_xor(s4, off);
        s5 += __shfl_xor(s5, off);
    }
    // ---- rot frame, redundantly in every lane (no broadcast needed) ----
    float ox = s0 + b0[0], oy = s1 + b0[1], oz = s2 + b0[2];
    float nx = s3 + b1[0], ny = s4 + b1[1], nz = s5 + b1[2];
    BN3(ox, oy, oz);
    BN3(nx, ny, nz);
    float rx = __fsub_rn(__fmul_rn(oy, nz), __fmul_rn(oz, ny));
    float ry = __fsub_rn(__fmul_rn(oz, nx), __fmul_rn(ox, nz));
    float rz = __fsub_rn(__fmul_rn(ox, ny), __fmul_rn(oy, nx));
    BN3(rx, ry, rz);
    float ax = __fsub_rn(__fmul_rn(ry, nz), __fmul_rn(rz, ny));
    float ay = __fsub_rn(__fmul_rn(rz, nx), __fmul_rn(rx, nz));
    float az = __fsub_rn(__fmul_rn(rx, ny), __fmul_rn(ry, nx));
    BN3(ax, ay, az);
    if (l == 0) {
        out[OFF_ORIS + p*3+0] = ox; out[OFF_ORIS + p*3+1] = oy; out[OFF_ORIS + p*3+2] = oz;
        out[OFF_NORS + p*3+0] = nx; out[OFF_NORS + p*3+1] = ny; out[OFF_NORS + p*3+2] = nz;
    }

    // ---- ballot loop with folded ordered extraction ----
    int count = 0, first = -1;
    for (int ch = 0; ch < 16 && count < NSM; ++ch) {
        int m = (ch << 6) + l;
        float mx = xb[m], my = xb[NP + m], mz = xb[2*NP + m];
        float mn = __fadd_rn(__fadd_rn(__fmul_rn(mx,mx), __fmul_rn(my,my)), __fmul_rn(mz,mz));
        float dot = __fadd_rn(__fadd_rn(__fmul_rn(cx,mx), __fmul_rn(cy,my)), __fmul_rn(cz,mz));
        float d = __fadd_rn(__fadd_rn(__fmul_rn(-2.0f, dot), cn), mn);
        bool sel = !(d > 0.09f);
        unsigned long long mk = __ballot(sel);
        if (first < 0 && mk != 0ull) first = (ch << 6) + (__ffsll(mk) - 1);
        if (sel) {
            int pos = count + (int)__popcll(mk & ((1ull << l) - 1ull));
            if (pos < NSM) sgidx[pos] = m;
        }
        count += (int)__popcll(mk);
    }
    __syncthreads();  // single-wave barrier (cheap); orders sgidx writes
    if (count < NSM) {
        for (int i2 = count + l; i2 < NSM; i2 += 64) sgidx[i2] = first;
    }
    __syncthreads();

    // ---- per-sample cell (lanes 0..47) + LDS atomicMax owner ----
    int cell = 0, msamp = 0;
    if (l < NSM) {
        msamp = sgidx[l];
        float lx = __fsub_rn(xb[msamp],        cx);
        float ly = __fsub_rn(xb[NP + msamp],   cy);
        float lz = __fsub_rn(xb[2*NP + msamp], cz);
        float lp0 = __fadd_rn(__fadd_rn(__fmul_rn(lx, ax), __fmul_rn(ly, ay)), __fmul_rn(lz, az));
        float lp1 = __fadd_rn(__fadd_rn(__fmul_rn(lx, rx), __fmul_rn(ly, ry)), __fmul_rn(lz, rz));
        float lp2 = __fadd_rn(__fadd_rn(__fmul_rn(lx, nx), __fmul_rn(ly, ny)), __fmul_rn(lz, nz));
        float t0 = rintf(__fmul_rn(__fdiv_rn(__fadd_rn(lp0, 0.3f), 0.6f), 6.0f));
        float t1 = rintf(__fmul_rn(__fdiv_rn(__fadd_rn(lp1, 0.3f), 0.6f), 6.0f));
        float t2 = rintf(__fmul_rn(__fdiv_rn(__fadd_rn(lp2, 0.3f), 0.6f), 6.0f));
        int c0 = (int)t0; c0 = c0 < 0 ? 0 : (c0 > 6 ? 6 : c0);
        int c1 = (int)t1; c1 = c1 < 0 ? 0 : (c1 > 6 ? 6 : c1);
        int c2 = (int)t2; c2 = c2 < 0 ? 0 : (c2 > 6 ? 6 : c2);
        cell = c0*NG + c1*NG + c2;
        atomicMax(&scell[cell], l);
    }
    __syncthreads();

    // ---- feat_off: serial over winning cells, full-wave 128-dot each ----
    bool winner = (l < NSM) && (scell[cell] == l);
    unsigned long long wmask = __ballot(winner);
    while (wmask) {
        int s = __ffsll(wmask) - 1;
        wmask &= wmask - 1;
        int cs = __shfl(cell, s);
        int ms = __shfl(msamp, s);
        int k = cs % NG, q = cs / NG;
        const float* fr = feat + (size_t)(b*NP + ms) * NC;
        const float* w0p = W_unet + l*(NG*3) + k*3;
        const float* w1p = W_unet + (64+l)*(NG*3) + k*3;
        float g0 = fr[l], g1 = fr[64+l];
        float p0 = g0*w0p[0] + g1*w1p[0];
        float p1 = g0*w0p[1] + g1*w1p[1];
        float p2 = g0*w0p[2] + g1*w1p[2];
        for (int off = 32; off; off >>= 1) {
            p0 += __shfl_xor(p0, off);
            p1 += __shfl_xor(p1, off);
            p2 += __shfl_xor(p2, off);
        }
        if (l == 0) {
            sfo[q*3+0] += p0;
            sfo[q*3+1] += p1;
            sfo[q*3+2] += p2;
        }
    }
    __syncthreads();

    // ---- up-projection + pts_up / pts_offset ----
    for (int t = l; t < NG*NG*3; t += 64) {
        int q = t / 3, d = t - q*3;
        int qi = q / NG, qj = q - qi*NG;
        float v0 = (float)((-30 + 10*qi) * 0.01);
        float v1 = (float)((-30 + 10*qj) * 0.01);
        float u0 = __fadd_rn(v0, sfo[q*3+0]);
        float u1 = __fadd_rn(v1, sfo[q*3+1]);
        float u2 = sfo[q*3+2];
        float r0d = (d == 0) ? ax : (d == 1) ? ay : az;
        float r1d = (d == 0) ? rx : (d == 1) ? ry : rz;
        float r2d = (d == 0) ? nx : (d == 1) ? ny : nz;
        float ctr = (d == 0) ? cx : (d == 1) ? cy : cz;
        float r = __fadd_rn(
                    __fadd_rn(
                      __fadd_rn(__fmul_rn(u0, r0d), __fmul_rn(u1, r1d)),
                      __fmul_rn(u2, r2d)),
                    ctr);
        spu[t] = r;
        out[OFF_PU + p*(NG*NG*3) + t] = r;
        if (q == 24) out[OFF_POFF + p*3 + d] = r;
    }
    __syncthreads();

    // ---- pts_ups gather ----
    if (l < 16*3) {
        int t = l / 3, d = l - t*3;
        int q = index[t];
        out[OFF_PUPS + (p*16 + t)*3 + d] = spu[q*3 + d];
    }
}

extern "C" void kernel_launch(void* const* d_in, const int* in_sizes, int n_in,
                              void* d_out, int out_size, void* d_ws, size_t ws_size,
                              hipStream_t stream) {
    const float* xyz    = (const float*)d_in[0];
    const float* feat   = (const float*)d_in[1];
    const float* W0     = (const float*)d_in[2];
    const float* b0     = (const float*)d_in[3];
    const float* W1     = (const float*)d_in[4];
    const float* b1     = (const float*)d_in[5];
    const float* W_unet = (const float*)d_in[6];
    const int*   index  = (const int*)d_in[7];
    float* out = (float*)d_out;

    hipLaunchKernelGGL(kfused, dim3(BN), dim3(64), 0, stream,
                       xyz, feat, W0, b0, W1, b1, W_unet, index, out);
}

// Round 7
// 78.784 us; speedup vs baseline: 1.0322x; 1.0322x over previous
//
#include <hip/hip_runtime.h>

#define NB 2
#define NP 1024
#define NC 128
#define NG 7
#define NSM 48
#define BN (NB*NP)

#define OFF_ORIS 0
#define OFF_NORS (BN*3)
#define OFF_PUPS (2*BN*3)
#define OFF_POFF (OFF_PUPS + BN*16*3)
#define OFF_PU   (OFF_POFF + BN*3)

__device__ __forceinline__ void bnorm3(float v[3]) {
    float ss = __fadd_rn(__fadd_rn(__fmul_rn(v[0],v[0]), __fmul_rn(v[1],v[1])), __fmul_rn(v[2],v[2]));
    float nr = sqrtf(__fadd_rn(ss, 1e-8f));
    float dn = __fadd_rn(nr, 1e-10f);
    v[0] = __fdiv_rn(v[0], dn);
    v[1] = __fdiv_rn(v[1], dn);
    v[2] = __fdiv_rn(v[2], dn);
}

// One block (256 thr) per point. No LDS point-cloud staging: xyz is 24 KB and
// L1-resident, so ballot/cell/upproj read it straight from global. 5 barriers.
__global__ __launch_bounds__(256) void kfused(const float* __restrict__ xyz,
                                              const float* __restrict__ feat,
                                              const float* __restrict__ W0, const float* __restrict__ b0,
                                              const float* __restrict__ W1, const float* __restrict__ b1,
                                              const float* __restrict__ W_unet,
                                              const int* __restrict__ index,
                                              float* __restrict__ out) {
    __shared__ float srot[9];
    __shared__ unsigned long long smask[16];
    __shared__ int   sgidx[NSM];
    __shared__ int   sidx[NSM];
    __shared__ int   scell[91];        // cell idx = 7*c0 + 7*c1 + c2 <= 90
    __shared__ float sfo[NG*NG*3];
    __shared__ float spu[NG*NG*3];

    int p = blockIdx.x;
    int b = p >> 10, n = p & (NP - 1);
    int tid = threadIdx.x;
    int w = tid >> 6, l = tid & 63;
    const float* xb = xyz + (size_t)b*3*NP;

    if (tid < NG*NG*3) sfo[tid] = 0.0f;
    if (tid < 91)      scell[tid] = -1;

    // center point (uniform across block -> scalarized)
    float cx = xb[n], cy = xb[NP + n], cz = xb[2*NP + n];
    float cn = __fadd_rn(__fadd_rn(__fmul_rn(cx,cx), __fmul_rn(cy,cy)), __fmul_rn(cz,cz));

    // ---- matvec (wave 0) overlapped with radius ballots (chunk 0 on wave 0 after matvec,
    //      chunks 1..15 on waves 1..3) ----
    if (w == 0) {
        float f0 = feat[p*NC + l];
        float f1 = feat[p*NC + 64 + l];
        float s0 = f0*W0[l]     + f1*W0[64+l];
        float s1 = f0*W0[128+l] + f1*W0[192+l];
        float s2 = f0*W0[256+l] + f1*W0[320+l];
        float s3 = f0*W1[l]     + f1*W1[64+l];
        float s4 = f0*W1[128+l] + f1*W1[192+l];
        float s5 = f0*W1[256+l] + f1*W1[320+l];
        for (int off = 32; off; off >>= 1) {
            s0 += __shfl_xor(s0, off);
            s1 += __shfl_xor(s1, off);
            s2 += __shfl_xor(s2, off);
            s3 += __shfl_xor(s3, off);
            s4 += __shfl_xor(s4, off);
            s5 += __shfl_xor(s5, off);
        }
        if (l == 0) {
            float o[3]  = { s0 + b0[0], s1 + b0[1], s2 + b0[2] };
            float nn[3] = { s3 + b1[0], s4 + b1[1], s5 + b1[2] };
            bnorm3(o);
            bnorm3(nn);
            float r90[3];
            r90[0] = __fsub_rn(__fmul_rn(o[1], nn[2]), __fmul_rn(o[2], nn[1]));
            r90[1] = __fsub_rn(__fmul_rn(o[2], nn[0]), __fmul_rn(o[0], nn[2]));
            r90[2] = __fsub_rn(__fmul_rn(o[0], nn[1]), __fmul_rn(o[1], nn[0]));
            bnorm3(r90);
            float o0[3];
            o0[0] = __fsub_rn(__fmul_rn(r90[1], nn[2]), __fmul_rn(r90[2], nn[1]));
            o0[1] = __fsub_rn(__fmul_rn(r90[2], nn[0]), __fmul_rn(r90[0], nn[2]));
            o0[2] = __fsub_rn(__fmul_rn(r90[0], nn[1]), __fmul_rn(r90[1], nn[0]));
            bnorm3(o0);

            out[OFF_ORIS + p*3+0] = o[0];  out[OFF_ORIS + p*3+1] = o[1];  out[OFF_ORIS + p*3+2] = o[2];
            out[OFF_NORS + p*3+0] = nn[0]; out[OFF_NORS + p*3+1] = nn[1]; out[OFF_NORS + p*3+2] = nn[2];

            srot[0] = o0[0];  srot[1] = o0[1];  srot[2] = o0[2];
            srot[3] = r90[0]; srot[4] = r90[1]; srot[5] = r90[2];
            srot[6] = nn[0];  srot[7] = nn[1];  srot[8] = nn[2];
        }
        // wave 0 handles ballot chunk 0
        {
            int m = l;
            float mx = xb[m], my = xb[NP + m], mz = xb[2*NP + m];
            float mn = __fadd_rn(__fadd_rn(__fmul_rn(mx,mx), __fmul_rn(my,my)), __fmul_rn(mz,mz));
            float dot = __fadd_rn(__fadd_rn(__fmul_rn(cx,mx), __fmul_rn(cy,my)), __fmul_rn(cz,mz));
            float d = __fadd_rn(__fadd_rn(__fmul_rn(-2.0f, dot), cn), mn);
            unsigned long long mk = __ballot(!(d > 0.09f));
            if (l == 0) smask[0] = mk;
        }
    } else {
        int ch0 = (w - 1) * 5 + 1;   // waves 1,2,3 -> chunks 1-5, 6-10, 11-15
        #pragma unroll
        for (int k = 0; k < 5; ++k) {
            int ch = ch0 + k;
            int m = (ch << 6) + l;
            float mx = xb[m], my = xb[NP + m], mz = xb[2*NP + m];
            float mn = __fadd_rn(__fadd_rn(__fmul_rn(mx,mx), __fmul_rn(my,my)), __fmul_rn(mz,mz));
            float dot = __fadd_rn(__fadd_rn(__fmul_rn(cx,mx), __fmul_rn(cy,my)), __fmul_rn(cz,mz));
            float d = __fadd_rn(__fadd_rn(__fmul_rn(-2.0f, dot), cn), mn);
            unsigned long long mk = __ballot(!(d > 0.09f));
            if (l == 0) smask[ch] = mk;
        }
    }
    __syncthreads();   // B1: smask + srot ready

    // ---- ordered first-48 extraction + pad (16 lanes) ----
    if (tid < 16) {
        unsigned long long wv = smask[tid];
        int prefix = 0, total = 0, firstj = 0;
        bool seen = false;
        #pragma unroll
        for (int j = 0; j < 16; ++j) {
            int pc = __popcll(smask[j]);
            if (j < tid) prefix += pc;
            if (!seen && pc) { firstj = j; seen = true; }
            total += pc;
        }
        int pos = prefix;
        while (wv && pos < NSM) {
            int bpos = __ffsll(wv) - 1;
            sgidx[pos++] = (tid << 6) + bpos;
            wv &= wv - 1;
        }
        if (total < NSM) {
            int first = (firstj << 6) + (__ffsll(smask[firstj]) - 1);
            for (int q2 = total + tid; q2 < NSM; q2 += 16) sgidx[q2] = first;
        }
    }
    __syncthreads();   // B2: sgidx ready

    // ---- per-sample cell + last-write-wins owner via atomicMax ----
    if (tid < NSM) {
        int m = sgidx[tid];
        float lx = __fsub_rn(xb[m],        cx);
        float ly = __fsub_rn(xb[NP + m],   cy);
        float lz = __fsub_rn(xb[2*NP + m], cz);
        int c[3];
        #pragma unroll
        for (int dd = 0; dd < 3; ++dd) {
            float lp = __fadd_rn(__fadd_rn(__fmul_rn(lx, srot[dd*3+0]),
                                           __fmul_rn(ly, srot[dd*3+1])),
                                 __fmul_rn(lz, srot[dd*3+2]));
            float t = rintf(__fmul_rn(__fdiv_rn(__fadd_rn(lp, 0.3f), 0.6f), 6.0f));
            int ci = (int)t;
            ci = ci < 0 ? 0 : (ci > 6 ? 6 : ci);
            c[dd] = ci;
        }
        int cell = c[0]*NG + c[1]*NG + c[2];
        sidx[tid] = cell;
        atomicMax(&scell[cell], tid);
    }
    __syncthreads();   // B3: owners ready

    // ---- feat_off: 16 lanes per sample, 16 samples per pass, 3 passes ----
    {
        int sl = tid & 15;
        int sg = tid >> 4;
        #pragma unroll
        for (int r = 0; r < 3; ++r) {
            int s = r*16 + sg;
            int cell = sidx[s];
            if (scell[cell] == s) {        // group-uniform predicate
                int k = cell % NG;
                int q = cell / NG;
                const float* fr = feat + (size_t)(b*NP + sgidx[s]) * NC;
                float p0 = 0.f, p1 = 0.f, p2 = 0.f;
                #pragma unroll
                for (int c8 = 0; c8 < 8; ++c8) {
                    int cc = sl + c8*16;
                    float f = fr[cc];
                    const float* wp = W_unet + cc*(NG*3) + k*3;
                    p0 += f * wp[0];
                    p1 += f * wp[1];
                    p2 += f * wp[2];
                }
                #pragma unroll
                for (int off = 8; off; off >>= 1) {
                    p0 += __shfl_xor(p0, off);
                    p1 += __shfl_xor(p1, off);
                    p2 += __shfl_xor(p2, off);
                }
                if (sl == 0) {
                    atomicAdd(&sfo[q*3+0], p0);
                    atomicAdd(&sfo[q*3+1], p1);
                    atomicAdd(&sfo[q*3+2], p2);
                }
            }
        }
    }
    __syncthreads();   // B4: sfo ready

    // ---- up-projection + outputs ----
    if (tid < NG*NG*3) {
        int q = tid / 3, d = tid % 3;
        int qi = q / NG, qj = q % NG;
        float v0 = (float)((-30 + 10*qi) * 0.01);
        float v1 = (float)((-30 + 10*qj) * 0.01);
        float u0 = __fadd_rn(v0, sfo[q*3+0]);
        float u1 = __fadd_rn(v1, sfo[q*3+1]);
        float u2 = sfo[q*3+2];
        float ctr = (d == 0) ? cx : (d == 1) ? cy : cz;
        float r = __fadd_rn(
                    __fadd_rn(
                      __fadd_rn(__fmul_rn(u0, srot[0*3+d]), __fmul_rn(u1, srot[1*3+d])),
                      __fmul_rn(u2, srot[2*3+d])),
                    ctr);
        spu[tid] = r;
        out[OFF_PU + p*(NG*NG*3) + tid] = r;
        if (q == 24) out[OFF_POFF + p*3 + d] = r;
    }
    __syncthreads();   // B5: spu ready

    if (tid < 16*3) {
        int t = tid / 3, d = tid % 3;
        int q = index[t];
        out[OFF_PUPS + (p*16 + t)*3 + d] = spu[q*3 + d];
    }
}

extern "C" void kernel_launch(void* const* d_in, const int* in_sizes, int n_in,
                              void* d_out, int out_size, void* d_ws, size_t ws_size,
                              hipStream_t stream) {
    const float* xyz    = (const float*)d_in[0];
    const float* feat   = (const float*)d_in[1];
    const float* W0     = (const float*)d_in[2];
    const float* b0     = (const float*)d_in[3];
    const float* W1     = (const float*)d_in[4];
    const float* b1     = (const float*)d_in[5];
    const float* W_unet = (const float*)d_in[6];
    const int*   index  = (const int*)d_in[7];
    float* out = (float*)d_out;

    hipLaunchKernelGGL(kfused, dim3(BN), dim3(256), 0, stream,
                       xyz, feat, W0, b0, W1, b1, W_unet, index, out);
}